// Round 1
// baseline (2462.011 us; speedup 1.0000x reference)
//
#include <hip/hip_runtime.h>

// LSTM autoencoder: 4 layers (72->64), (64->32), (32->64), (64->72), B=512, T=512, fp32.
// One block per batch sequence; gate-per-thread; weight rows in VGPRs; xh in LDS
// (broadcast float4 reads); input GEMM folded into the recurrent dot.

#define B_ 512
#define T_ 512

__device__ __forceinline__ float fast_sigmoid(float x) {
    return 1.0f / (1.0f + __expf(-x));
}
__device__ __forceinline__ float fast_tanh(float x) {
    // 1 - 2/(e^{2x}+1): saturates correctly to +/-1 for large |x|, no NaN.
    return 1.0f - 2.0f / (__expf(2.0f * x) + 1.0f);
}

template <int IN, int H, int BLOCK, int MINWAVES>
__global__ __launch_bounds__(BLOCK, MINWAVES)
void lstm_layer_kernel(const float* __restrict__ x,    // [B, T, IN]
                       const float* __restrict__ Wih,  // [4H, IN]
                       const float* __restrict__ Whh,  // [4H, H]
                       const float* __restrict__ bih,  // [4H]
                       const float* __restrict__ bhh,  // [4H]
                       float* __restrict__ out)        // [B, T, H]
{
    constexpr int G   = 4 * H;        // gate count
    constexpr int KW  = IN + H;       // dot length over [x_t | h]
    constexpr int KW4 = KW / 4;
    constexpr int IN4 = IN / 4;
    static_assert(KW % 4 == 0 && IN % 4 == 0 && H % 4 == 0, "vec4 layout");
    static_assert((IN * 4) % 16 == 0, "h-region stays 16B aligned");

    __shared__ __align__(16) float xh[KW];   // [ x_t (IN) | h_{t-1} (H) ]
    __shared__ float gates[G];

    const int tid = threadIdx.x;
    const int b   = blockIdx.x;

    // ---- load this thread's weight row into registers (one-time) ----
    float4 w4[KW4];
    float  bias = 0.0f;
    if (tid < G) {
        const float4* wi = reinterpret_cast<const float4*>(Wih + tid * IN);
#pragma unroll
        for (int k = 0; k < IN4; ++k) w4[k] = wi[k];
        const float4* wh = reinterpret_cast<const float4*>(Whh + tid * H);
#pragma unroll
        for (int k = 0; k < H / 4; ++k) w4[IN4 + k] = wh[k];
        bias = bih[tid] + bhh[tid];
    }

    // ---- init state ----
    if (tid < H) xh[IN + tid] = 0.0f;
    float c = 0.0f;

    const float4* xg   = reinterpret_cast<const float4*>(x + (size_t)b * T_ * IN);
    float4*       xh4w = reinterpret_cast<float4*>(xh);
    const float4* xh4  = reinterpret_cast<const float4*>(xh);
    float*        outb = out + (size_t)b * T_ * H;

    // prefetch x_0
    float4 xreg;
    if (tid < IN4) xreg = xg[tid];

    for (int t = 0; t < T_; ++t) {
        // stage x_t (stager threads; disjoint LDS region from h-updates)
        if (tid < IN4) xh4w[tid] = xreg;
        __syncthreads();  // A: x_t + h_{t-1} visible to everyone

        // prefetch x_{t+1}; latency hidden across the dot phase
        if (t + 1 < T_ && tid < IN4) xreg = xg[(t + 1) * IN4 + tid];

        if (tid < G) {
            float a0 = bias, a1 = 0.0f, a2 = 0.0f, a3 = 0.0f;
#pragma unroll
            for (int k = 0; k < KW4; ++k) {
                float4 v = xh4[k];  // broadcast read: all lanes same address
                a0 += w4[k].x * v.x;
                a1 += w4[k].y * v.y;
                a2 += w4[k].z * v.z;
                a3 += w4[k].w * v.w;
            }
            float acc = (a0 + a1) + (a2 + a3);
            // PyTorch gate order: rows [0,H)=i, [H,2H)=f, [2H,3H)=g, [3H,4H)=o
            float val = (tid >= 2 * H && tid < 3 * H) ? fast_tanh(acc)
                                                      : fast_sigmoid(acc);
            gates[tid] = val;
        }
        __syncthreads();  // B: all gates visible

        if (tid < H) {
            float i  = gates[tid];
            float f  = gates[tid + H];
            float g  = gates[tid + 2 * H];
            float o  = gates[tid + 3 * H];
            c = f * c + i * g;
            float hv = o * fast_tanh(c);
            xh[IN + tid]     = hv;   // next step's h (readers wait at barrier A)
            outb[t * H + tid] = hv;  // coalesced across threads
        }
    }
}

extern "C" void kernel_launch(void* const* d_in, const int* in_sizes, int n_in,
                              void* d_out, int out_size, void* d_ws, size_t ws_size,
                              hipStream_t stream) {
    const float* x = (const float*)d_in[0];
    // e1: in[1..4], e2: in[5..8], d1: in[9..12], d2: in[13..16]
    const float* e1_Wih = (const float*)d_in[1];
    const float* e1_Whh = (const float*)d_in[2];
    const float* e1_bih = (const float*)d_in[3];
    const float* e1_bhh = (const float*)d_in[4];
    const float* e2_Wih = (const float*)d_in[5];
    const float* e2_Whh = (const float*)d_in[6];
    const float* e2_bih = (const float*)d_in[7];
    const float* e2_bhh = (const float*)d_in[8];
    const float* d1_Wih = (const float*)d_in[9];
    const float* d1_Whh = (const float*)d_in[10];
    const float* d1_bih = (const float*)d_in[11];
    const float* d1_bhh = (const float*)d_in[12];
    const float* d2_Wih = (const float*)d_in[13];
    const float* d2_Whh = (const float*)d_in[14];
    const float* d2_bih = (const float*)d_in[15];
    const float* d2_bhh = (const float*)d_in[16];

    float* outp = (float*)d_out;

    // Scratch layout: ws0 = e2 out [512,512,32] (32 MB), ws1 = d1 out [512,512,64] (64 MB).
    // e1 out (64 MB) borrows d_out (75.5 MB) as scratch; d2 overwrites d_out with the
    // final [512,512,72] output (reads ws1, no overlap).
    float* ws0 = (float*)d_ws;                               // 32 MB
    float* ws1 = (float*)((char*)d_ws + (size_t)B_ * T_ * 32 * sizeof(float));  // 64 MB

    // Layer e1: 72 -> 64
    lstm_layer_kernel<72, 64, 256, 2><<<B_, 256, 0, stream>>>(
        x, e1_Wih, e1_Whh, e1_bih, e1_bhh, outp);
    // Layer e2: 64 -> 32
    lstm_layer_kernel<64, 32, 128, 2><<<B_, 128, 0, stream>>>(
        outp, e2_Wih, e2_Whh, e2_bih, e2_bhh, ws0);
    // Layer d1: 32 -> 64
    lstm_layer_kernel<32, 64, 256, 2><<<B_, 256, 0, stream>>>(
        ws0, d1_Wih, d1_Whh, d1_bih, d1_bhh, ws1);
    // Layer d2: 64 -> 72 (288 gates -> 320 threads; cap VGPRs so 2 blocks/CU fit)
    lstm_layer_kernel<64, 72, 320, 3><<<B_, 320, 0, stream>>>(
        ws1, d2_Wih, d2_Whh, d2_bih, d2_bhh, outp);
}